// Round 1
// 3083.257 us; speedup vs baseline: 1.2781x; 1.2781x over previous
//
// T-LSTM persistent-recurrence kernel for MI355X (gfx950) — round 3.
//
// Round 2 post-mortem: 7.5 us/step with all pipes idle. Theory: relaxed
// agent-scope atomic loads (state exchange via L3) are kept in program
// order by LLVM and each MFMA / ds_write forces a waitcnt before the next
// load issues -> 16+ serialized L3 round trips per step (~10-15k cycles).
//
// Round 3: register-batched issue of ALL agent-scope loads (pay L3
// latency once per phase): c_s wave prefetches its 32 u64 c-loads into
// regs before the MFMA loop; h-staging threads prefetch 8 u64 each before
// the ds_writes; x row batched as 16 float4 before conversion. bf16
// conversion via v_cvt_pk_bf16_f32 (RNE, same as old bit-trick). out
// stores moved after the flag store (off the pre-flag vmcnt drain).
// Prep kernel now a 32x32 LDS-tiled transpose (both sides coalesced).

#include <hip/hip_runtime.h>

typedef unsigned short u16;
typedef unsigned int u32;
typedef unsigned long long u64;
typedef __attribute__((ext_vector_type(8))) short short8;
typedef __attribute__((ext_vector_type(4))) float f32x4;

constexpr int BATCH = 128, SEQ = 512, ISZ = 256, HSZ = 512, G4H = 2048;
constexpr int KZ   = ISZ + HSZ;                 // 768
constexpr int NGRP = 8,  MR  = BATCH / NGRP;    // 16 rows per group
constexpr int NCW  = 32, CPW = HSZ / NCW;       // 16 cols per WG
constexpr int LDBZ = KZ + 8, LDBC = HSZ + 8, LDH = HSZ + 8;
constexpr int BH   = BATCH * HSZ;               // 65536
constexpr size_t BSH = (size_t)BATCH * SEQ * HSZ;

// workspace layout (bytes)
constexpr size_t WUT_OFF = 0;                                  // 2048*768*2
constexpr size_t WDT_OFF = WUT_OFF + (size_t)G4H * KZ * 2;     // 512*512*2
constexpr size_t HBF_OFF = WDT_OFF + (size_t)HSZ * HSZ * 2;    // h bf16 x2
constexpr size_t CBF_OFF = HBF_OFF + (size_t)2 * BH * 2;       // c bf16 x2
constexpr size_t FLG_OFF = CBF_OFF + (size_t)2 * BH * 2;       // 256 ints

// LDS layout (bytes)
constexpr int BZ_OFF  = 0;                       // [64][LDBZ] u16
constexpr int BC_OFF  = BZ_OFF  + 64 * LDBZ * 2; // [16][LDBC] u16
constexpr int HS_OFF  = BC_OFF  + 16 * LDBC * 2; // [MR][LDH]  u16
constexpr int ZS_OFF  = HS_OFF  + MR * LDH * 2;  // [5][16][16] f32
constexpr int CFL_OFF = ZS_OFF  + 5 * 256 * 4;   // [16][16] f32
constexpr int BL_OFF  = CFL_OFF + MR * CPW * 4;  // [5][16] f32
constexpr int LDS_BYTES = BL_OFF + 5 * CPW * 4;  // 139072

__device__ __forceinline__ u16 f2bf(float f) {
  unsigned u = __float_as_uint(f);
  u += 0x7fffu + ((u >> 16) & 1u);   // RNE
  return (u16)(u >> 16);
}

// hardware packed f32x2 -> bf16x2 (RNE), lo in bits [15:0]
__device__ __forceinline__ u32 cvtpk(float lo, float hi) {
  u32 r;
  asm("v_cvt_pk_bf16_f32 %0, %1, %2" : "=v"(r) : "v"(lo), "v"(hi));
  return r;
}

__device__ __forceinline__ short8 cvt_bf8(float4 a, float4 b) {
  union { u32 u[4]; short8 s; } v;
  v.u[0] = cvtpk(a.x, a.y);
  v.u[1] = cvtpk(a.z, a.w);
  v.u[2] = cvtpk(b.x, b.y);
  v.u[3] = cvtpk(b.z, b.w);
  return v.s;
}

__device__ __forceinline__ u64 ld_at64(const void* p) {
  return __hip_atomic_load((const u64*)p, __ATOMIC_RELAXED,
                           __HIP_MEMORY_SCOPE_AGENT);
}
__device__ __forceinline__ void st_at64(void* p, u64 v) {
  __hip_atomic_store((u64*)p, v, __ATOMIC_RELAXED, __HIP_MEMORY_SCOPE_AGENT);
}
__device__ __forceinline__ void st_at32(void* p, u32 v) {
  __hip_atomic_store((u32*)p, v, __ATOMIC_RELAXED, __HIP_MEMORY_SCOPE_AGENT);
}
__device__ __forceinline__ short8 ld_bf8_at(const u16* p) {
  union { u64 u[2]; short8 s; } v;
  v.u[0] = ld_at64(p);
  v.u[1] = ld_at64(p + 4);
  return v.s;
}

__device__ __forceinline__ float sig_f(float x)  { return 1.f / (1.f + __expf(-x)); }
__device__ __forceinline__ float tanh_f(float x) { return 1.f - 2.f / (1.f + __expf(2.f * x)); }

// ---- prep: tiled transpose W||U -> wut (2048x768 bf16), Wd -> wdt ----
constexpr int TJ1 = G4H / 32;       // 64
constexpr int TK1 = KZ / 32;        // 24
constexpr int NT1 = TJ1 * TK1;      // 1536
constexpr int TJ2 = HSZ / 32;       // 16
constexpr int NT2 = TJ2 * TJ2;      // 256

__global__ void tlstm_prep(const float* __restrict__ W, const float* __restrict__ U,
                           const float* __restrict__ Wd,
                           u16* __restrict__ wut, u16* __restrict__ wdt,
                           int* __restrict__ flags) {
  __shared__ float tb[32][33];
  const int tid = threadIdx.x;
  const int c = tid & 31, r = tid >> 5;       // 256 thr: r 0..7
  const int tile = blockIdx.x;
  if (tile == 0 && tid < 256) flags[tid] = 0; // deterministic sync state
  if (tile < NT1) {
    const int tj = tile % TJ1, tk = tile / TJ1;
    const int j0 = tj * 32, k0 = tk * 32;
#pragma unroll
    for (int rr = r; rr < 32; rr += 8) {
      const int k = k0 + rr;
      tb[rr][c] = (k < ISZ) ? W[(size_t)k * G4H + j0 + c]
                            : U[(size_t)(k - ISZ) * G4H + j0 + c];
    }
    __syncthreads();
#pragma unroll
    for (int rr = r; rr < 32; rr += 8)
      wut[(size_t)(j0 + rr) * KZ + k0 + c] = f2bf(tb[c][rr]);
  } else {
    const int t2 = tile - NT1;
    const int tj = t2 % TJ2, tk = t2 / TJ2;
    const int j0 = tj * 32, k0 = tk * 32;
#pragma unroll
    for (int rr = r; rr < 32; rr += 8)
      tb[rr][c] = Wd[(size_t)(k0 + rr) * HSZ + j0 + c];
    __syncthreads();
#pragma unroll
    for (int rr = r; rr < 32; rr += 8)
      wdt[(size_t)(j0 + rr) * HSZ + k0 + c] = f2bf(tb[c][rr]);
  }
}

__global__ void __launch_bounds__(320, 1)
tlstm_rec(const float* __restrict__ x, const float* __restrict__ dtp,
          const float* __restrict__ bias, const float* __restrict__ bd,
          const u16* __restrict__ wut, const u16* __restrict__ wdt,
          u16* hbf, u16* cbf, int* flags, float* out) {
  extern __shared__ char lds[];
  u16*   Bz  = (u16*)(lds + BZ_OFF);
  u16*   Bc  = (u16*)(lds + BC_OFF);
  u16*   hs  = (u16*)(lds + HS_OFF);
  float* zs  = (float*)(lds + ZS_OFF);
  float* cfl = (float*)(lds + CFL_OFF);
  float* bl  = (float*)(lds + BL_OFF);

  const int tid  = threadIdx.x;
  const int grp  = blockIdx.x >> 5;     // batch group 0..7
  const int cwg  = blockIdx.x & 31;     // column WG 0..31
  const int G0   = grp * MR;
  const int C0   = cwg * CPW;
  const int wave = tid >> 6, lane = tid & 63;
  const int m16  = lane & 15, quad = lane >> 4;

  // ---- stage weights into LDS (once) ----
  {
    const unsigned* src = (const unsigned*)wut;
    unsigned* dst = (unsigned*)Bz;
    for (int i = tid; i < 64 * (KZ / 2); i += 320) {
      int gc = i / (KZ / 2), d = i - gc * (KZ / 2);
      int zc = (gc >> 4) * HSZ + C0 + (gc & 15);   // gate-major z column
      dst[gc * (LDBZ / 2) + d] = src[zc * (KZ / 2) + d];
    }
    const unsigned* s2 = (const unsigned*)wdt;
    unsigned* d2 = (unsigned*)Bc;
    for (int i = tid; i < 16 * (HSZ / 2); i += 320) {
      int r = i >> 8, d = i & 255;
      d2[r * (LDBC / 2) + d] = s2[(C0 + r) * (HSZ / 2) + d];
    }
  }
  // biases -> LDS
  if (tid < 80) {
    int j = tid >> 4, c = tid & 15;
    bl[tid] = (j < 4) ? bias[j * HSZ + C0 + c] : bd[C0 + c];
  }
  // fp32 c master (WG-private) -> zero
  if (tid < 256) cfl[tid] = 0.f;
  // zero group's state rows in buffer 0 (all col-WGs write same zeros)
  {
    u64* h0 = (u64*)(hbf + (size_t)G0 * HSZ);
    u64* c0 = (u64*)(cbf + (size_t)G0 * HSZ);
    for (int i = tid; i < MR * HSZ / 4; i += 320) {
      st_at64(h0 + i, 0ull);
      st_at64(c0 + i, 0ull);
    }
  }
  __syncthreads();   // drains vmcnt: zeros at L3 before t=0 reads

  const int* fbase = flags + grp * 32;
  const float* xbase = x + (size_t)(G0 + m16) * SEQ * ISZ + quad * 8;

  for (int t = 0; t < SEQ; ++t) {
    const int p = t & 1, q = p ^ 1;
    const u16* hA = hbf + (size_t)p * BH;
    const u16* cA = cbf + (size_t)p * BH;
    u16* hQ = hbf + (size_t)q * BH;
    u16* cQ = cbf + (size_t)q * BH;

    float dtv = 0.f;
    if (tid < 128)
      dtv = dtp[(size_t)(G0 + (tid >> 3)) * SEQ + t];   // early issue

    f32x4 acc = {0.f, 0.f, 0.f, 0.f};

    if (wave < 4) {
      // ---- batched issue: 16 float4 (x row) then 8 u64 (h tile slice).
      // All vmem issues back-to-back; L3/HBM latency paid once. ----
      const float* xt = xbase + (size_t)t * ISZ;
      float4 xa[16];
#pragma unroll
      for (int kt = 0; kt < 8; ++kt) {
        xa[2 * kt]     = *(const float4*)(xt + kt * 32);
        xa[2 * kt + 1] = *(const float4*)(xt + kt * 32 + 4);
      }
      const u64* src = (const u64*)(hA + (size_t)G0 * HSZ);
      u64 hv[8];
#pragma unroll
      for (int j = 0; j < 8; ++j)
        hv[j] = ld_at64(src + tid + j * 256);

      // gate wave g: x_t @ W part (K 0..255) while h loads fly
      const u16* bz = Bz + (size_t)(wave * 16 + m16) * LDBZ + quad * 8;
#pragma unroll
      for (int kt = 0; kt < 8; ++kt) {
        short8 a = cvt_bf8(xa[2 * kt], xa[2 * kt + 1]);
        short8 b = *(const short8*)(bz + kt * 32);
        acc = __builtin_amdgcn_mfma_f32_16x16x32_bf16(a, b, acc, 0, 0, 0);
      }
      // stage h tile into LDS (de-duplicated, 256 threads x 8 u64)
      u64* dst = (u64*)hs;
#pragma unroll
      for (int j = 0; j < 8; ++j) {
        int i = tid + j * 256;
        dst[(i >> 7) * (LDH / 4) + (i & 127)] = hv[j];
      }
    } else {
      // c_s wave: batched c row loads (32 u64 -> regs), then GEMM vs Bc
      const u16* cp = cA + (size_t)(G0 + m16) * HSZ + quad * 8;
      short8 ca[16];
#pragma unroll
      for (int kt = 0; kt < 16; ++kt)
        ca[kt] = ld_bf8_at(cp + kt * 32);
      const u16* bc = Bc + (size_t)m16 * LDBC + quad * 8;
#pragma unroll
      for (int kt = 0; kt < 16; ++kt) {
        short8 b = *(const short8*)(bc + kt * 32);
        acc = __builtin_amdgcn_mfma_f32_16x16x32_bf16(ca[kt], b, acc, 0, 0, 0);
      }
#pragma unroll
      for (int i = 0; i < 4; ++i)
        zs[4 * 256 + (quad * 4 + i) * 16 + m16] = acc[i];
    }
    __syncthreads();   // hs staged (+ zs[4] written)

    if (wave < 4) {
      // gate wave g: h @ U part (K 256..767) from LDS
      const u16* bz2 = Bz + (size_t)(wave * 16 + m16) * LDBZ + 256 + quad * 8;
      const u16* hp  = hs + (size_t)m16 * LDH + quad * 8;
#pragma unroll
      for (int kt = 0; kt < 16; ++kt) {
        short8 a = *(const short8*)(hp + kt * 32);
        short8 b = *(const short8*)(bz2 + kt * 32);
        acc = __builtin_amdgcn_mfma_f32_16x16x32_bf16(a, b, acc, 0, 0, 0);
      }
#pragma unroll
      for (int i = 0; i < 4; ++i)
        zs[wave * 256 + (quad * 4 + i) * 16 + m16] = acc[i];
    }
    __syncthreads();   // zs complete

    // ---- element-wise T-LSTM update: 16 rows x 16 cols, col-pairs ----
    float rh0 = 0.f, rh1 = 0.f, rc0 = 0.f, rc1 = 0.f;
    int row = 0, ch = 0;
    if (tid < 128) {
      const int lr  = tid >> 3;          // local row 0..15
      const int cp2 = (tid & 7) * 2;     // even local col
      row = G0 + lr;
      ch  = C0 + cp2;
      const float gdec = 1.f / __logf(2.718281828459045f + dtv);
      float rh[2], rc[2];
#pragma unroll
      for (int u = 0; u < 2; ++u) {
        const int c = cp2 + u;
        const int zb = lr * 16 + c;
        float zi = zs[0 * 256 + zb] + bl[0 * 16 + c];
        float zf = zs[1 * 256 + zb] + bl[1 * 16 + c];
        float zo = zs[2 * 256 + zb] + bl[2 * 16 + c];
        float zc = zs[3 * 256 + zb] + bl[3 * 16 + c];
        float s  = zs[4 * 256 + zb] + bl[4 * 16 + c];
        float cprev = cfl[zb];
        float cs = tanh_f(s);
        float cadj = cprev - cs + cs * gdec;
        float ig = sig_f(zi), fg = sig_f(zf), og = sig_f(zo);
        float ct = tanh_f(zc);
        float cnew = fg * cadj + ig * ct;
        float hnew = og * tanh_f(cnew);
        cfl[zb] = cnew;
        rh[u] = hnew; rc[u] = cnew;
      }
      rh0 = rh[0]; rh1 = rh[1]; rc0 = rc[0]; rc1 = rc[1];
      // state stores only: these are what the pre-flag drain must cover
      st_at32(hQ + (size_t)row * HSZ + ch, cvtpk(rh0, rh1));
      st_at32(cQ + (size_t)row * HSZ + ch, cvtpk(rc0, rc1));
    }

    // ---- fence-free per-group barrier ----
    if (t < SEQ - 1) {
      __syncthreads();   // state stores drained (vmcnt 0)
      __asm__ volatile("" ::: "memory");
      if (tid == 0)
        __hip_atomic_store(&flags[grp * 32 + cwg], t + 2,
                           __ATOMIC_RELAXED, __HIP_MEMORY_SCOPE_AGENT);
      // out stores AFTER the flag: off the critical drain, hide under spin
      if (tid < 128) {
        float2 hv2; hv2.x = rh0; hv2.y = rh1;
        *(float2*)(out + ((size_t)row * SEQ + t) * HSZ + ch) = hv2;
      }
      for (;;) {
        int v = (lane < 32)
                    ? __hip_atomic_load(fbase + lane, __ATOMIC_RELAXED,
                                        __HIP_MEMORY_SCOPE_AGENT)
                    : 0x7fffffff;
        if (__all(v >= t + 2)) break;
        __builtin_amdgcn_s_sleep(1);
      }
      __asm__ volatile("" ::: "memory");
    } else {
      if (tid < 128) {
        float2 hv2; hv2.x = rh0; hv2.y = rh1;
        float2 cv2; cv2.x = rc0; cv2.y = rc1;
        *(float2*)(out + ((size_t)row * SEQ + t) * HSZ + ch) = hv2;
        *(float2*)(out + BSH + (size_t)row * HSZ + ch) = hv2;       // h_t
        *(float2*)(out + BSH + BH + (size_t)row * HSZ + ch) = cv2;  // c_t
      }
    }
  }
}

extern "C" void kernel_launch(void* const* d_in, const int* in_sizes, int n_in,
                              void* d_out, int out_size, void* d_ws, size_t ws_size,
                              hipStream_t stream) {
  (void)in_sizes; (void)n_in; (void)out_size; (void)ws_size;
  const float* x  = (const float*)d_in[0];
  const float* dt = (const float*)d_in[1];
  const float* W  = (const float*)d_in[2];
  const float* U  = (const float*)d_in[3];
  const float* b  = (const float*)d_in[4];
  const float* Wd = (const float*)d_in[5];
  const float* bd = (const float*)d_in[6];
  float* out = (float*)d_out;
  char*  ws  = (char*)d_ws;

  u16* wut   = (u16*)(ws + WUT_OFF);
  u16* wdt   = (u16*)(ws + WDT_OFF);
  u16* hbf   = (u16*)(ws + HBF_OFF);
  u16* cbf   = (u16*)(ws + CBF_OFF);
  int* flags = (int*)(ws + FLG_OFF);

  tlstm_prep<<<NT1 + NT2, 256, 0, stream>>>(W, U, Wd, wut, wdt, flags);

  hipFuncSetAttribute((const void*)tlstm_rec,
                      hipFuncAttributeMaxDynamicSharedMemorySize, LDS_BYTES);
  tlstm_rec<<<NGRP * NCW, 320, LDS_BYTES, stream>>>(
      x, dt, b, bd, wut, wdt, hbf, cbf, flags, out);
}